// Round 8
// baseline (194.606 us; speedup 1.0000x reference)
//
#include <hip/hip_runtime.h>

#define H 128

typedef __bf16 bf16x8 __attribute__((ext_vector_type(8)));
typedef __bf16 bf16x4 __attribute__((ext_vector_type(4)));
typedef float  f32x4  __attribute__((ext_vector_type(4)));

__device__ __forceinline__ int gate_to_gi(int g) {
    // GATE_CODES = (2, 3, 4, 1) -> gi 0..3
    switch (g) {
        case 2: return 0;
        case 3: return 1;
        case 4: return 2;
        case 1: return 3;
        default: return -1;
    }
}

// ---------------- fast zero (replaces 41us rocclr fillBuffer for L2-resident region) ----------------
__global__ __launch_bounds__(256)
void zero_ws(f32x4* __restrict__ p, int n16) {
    int i = blockIdx.x * blockDim.x + threadIdx.x;
    f32x4 z = {};
    for (; i < n16; i += gridDim.x * blockDim.x) p[i] = z;
}

// ---------------- node buckets + degree histograms ----------------
#define BB_CHUNK 2048
__global__ __launch_bounds__(256)
void bucket_build(const int* __restrict__ gate, const int* __restrict__ ei,
                  const int* __restrict__ lvl, int E, int N,
                  int* __restrict__ ncnt, int* __restrict__ nbuf, int ncap,
                  int* __restrict__ cnt_in, int* __restrict__ cnt_out) {
    __shared__ int lcnt[8];
    __shared__ int lbase[8];
    const int tid = threadIdx.x;
    const int total = max(E, N);

    for (int chunk = blockIdx.x * BB_CHUNK; chunk < total; chunk += gridDim.x * BB_CHUNK) {
        if (tid < 8) lcnt[tid] = 0;
        __syncthreads();
        int nbkt[8], npos[8];
        #pragma unroll
        for (int it = 0; it < 8; ++it) {
            int i = chunk + it * 256 + tid;
            nbkt[it] = -1;
            if (i < E) {
                int s = ei[i], d = ei[E + i];
                atomicAdd(&cnt_in[d * 6 + gate[s]], 1);
                atomicAdd(&cnt_out[s * 6 + gate[d]], 1);
            }
            if (i < N) {
                int gi = gate_to_gi(gate[i]);
                int L = lvl[i];
                if (gi >= 0 && L >= 1 && L <= 2) {
                    int b = (L - 1) * 4 + gi;
                    nbkt[it] = b;
                    npos[it] = atomicAdd(&lcnt[b], 1);
                }
            }
        }
        __syncthreads();
        if (tid < 8) lbase[tid] = atomicAdd(&ncnt[tid], lcnt[tid]);
        __syncthreads();
        #pragma unroll
        for (int it = 0; it < 8; ++it) {
            int i = chunk + it * 256 + tid;
            if (nbkt[it] >= 0) {
                int p = lbase[nbkt[it]] + npos[it];
                if (p < ncap) nbuf[nbkt[it] * ncap + p] = i;
            }
        }
        __syncthreads();
    }
}

// ---------------- per-bucket prefix-sum of in-degrees -> per-node cursor + bucket edge totals ----------------
__global__ __launch_bounds__(256)
void node_scan(const int* __restrict__ ncnt, const int* __restrict__ nbuf, int ncap,
               const int* __restrict__ cnt_in, int ecap,
               int* __restrict__ cursor, int* __restrict__ etot) {
    const int b = blockIdx.x;   // 0..7
    const int tid = threadIdx.x;
    const int cnt = min(ncnt[b], ncap);
    __shared__ int sA[256], sB[256];
    __shared__ int running;
    if (tid == 0) running = 0;
    __syncthreads();
    for (int base = 0; base < cnt; base += 256) {
        int p = base + tid;
        int d = 0, n = -1;
        if (p < cnt) {
            n = nbuf[b * ncap + p];
            #pragma unroll
            for (int c = 0; c < 6; ++c) d += cnt_in[n * 6 + c];
        }
        sA[tid] = d;
        __syncthreads();
        int* src = sA; int* dst = sB;
        #pragma unroll
        for (int off = 1; off < 256; off <<= 1) {
            int v = src[tid];
            if (tid >= off) v += src[tid - off];
            dst[tid] = v;
            __syncthreads();
            int* tmp = src; src = dst; dst = tmp;
        }
        int incl = src[tid];
        int excl = incl - d;
        int rbase = running;
        if (p < cnt) cursor[n] = b * ecap + rbase + excl;
        __syncthreads();
        if (tid == 0) running = rbase + src[255];
        __syncthreads();
    }
    if (tid == 0) etot[b] = running;
}

// ---------------- scatter (src,dst) into per-node (dst-sorted) edge lists ----------------
__global__ __launch_bounds__(256)
void edge_scatter(const int* __restrict__ gate, const int* __restrict__ ei,
                  const int* __restrict__ lvl, int E,
                  int* __restrict__ cursor, int2* __restrict__ elist) {
    int e = blockIdx.x * blockDim.x + threadIdx.x;
    if (e >= E) return;
    int d = ei[E + e];
    int gi = gate_to_gi(gate[d]);
    if (gi < 0) return;
    int L = lvl[d];
    if (L < 1 || L > 2) return;
    int slot = atomicAdd(&cursor[d], 1);
    elist[slot] = make_int2(ei[e], d);
}

// ---------------- weight prep: transpose + bf16 ----------------
__global__ void prep_weights(const float* __restrict__ aW1, const float* __restrict__ aW2,
                             const float* __restrict__ gWih, const float* __restrict__ hsW,
                             __bf16* __restrict__ W1T, __bf16* __restrict__ W2T,
                             __bf16* __restrict__ WihT, __bf16* __restrict__ hsWT) {
    int z = blockIdx.z;
    const float* src;
    __bf16* dst;
    int shiftK, C;
    if (z < 4)       { src = aW1 + (size_t)z * 256 * 128;      dst = W1T + (size_t)z * 128 * 256; shiftK = 8; C = 128; }
    else if (z < 8)  { src = aW2 + (size_t)(z - 4) * 128 * 128; dst = W2T + (size_t)(z - 4) * 128 * 128; shiftK = 7; C = 128; }
    else if (z < 12) { src = gWih + (size_t)(z - 8) * 128 * 384; dst = WihT + (size_t)(z - 8) * 384 * 128; shiftK = 7; C = 384; }
    else             { src = hsW;                               dst = hsWT;                       shiftK = 8; C = 128; }
    int K = 1 << shiftK;
    int total = K * C;
    int idx = blockIdx.x * blockDim.x + threadIdx.x;
    if (idx >= total) return;
    int c = idx >> shiftK;
    int k = idx & (K - 1);
    dst[(size_t)c * K + k] = (__bf16)src[(size_t)k * C + c];
}

// ---------------- encoder: s,t + hs = [s,t]@hsW (MFMA); writes out(f32, incl. hf=0 for
//                  non-bucketed nodes) + mir(bf16, hf half zeroed); zeroes agg rows of bucketed nodes ----------------
__global__ __launch_bounds__(256, 2)
void encoder_mfma(const int* __restrict__ gate, const int* __restrict__ lvl,
                  const int* __restrict__ cnt_in, const int* __restrict__ cnt_out,
                  const float* __restrict__ Ws_self, const float* __restrict__ Ws_nbr,
                  const float* __restrict__ Wt_self, const float* __restrict__ Wt_nbr,
                  const __bf16* __restrict__ hsWT, const float* __restrict__ hs_b,
                  float* __restrict__ out, __bf16* __restrict__ mir,
                  float* __restrict__ agg, int N) {
    __shared__ __bf16 st[16][264];
    const int tid = threadIdx.x;
    const int lane = tid & 63;
    const int w = tid >> 6;
    const int row = tid >> 4;      // 0..15
    const int c0 = (tid & 15) * 8; // col chunk

    bf16x8 bw[8][2];
    #pragma unroll
    for (int kk = 0; kk < 8; ++kk)
        #pragma unroll
        for (int j = 0; j < 2; ++j) {
            int col = w * 32 + j * 16 + (lane & 15);
            bw[kk][j] = *(const bf16x8*)&hsWT[(size_t)col * 256 + kk * 32 + (lane >> 4) * 8];
        }
    float hbc[2];
    #pragma unroll
    for (int j = 0; j < 2; ++j) hbc[j] = hs_b[w * 32 + j * 16 + (lane & 15)];

    const int ntiles = (N + 15) >> 4;
    for (int t = blockIdx.x; t < ntiles; t += gridDim.x) {
        const int base = t * 16;
        int n = base + row;
        if (n >= N) n = N - 1;
        const int g = gate[n];
        const int L = lvl[n];
        int cin[6], cout[6];
        #pragma unroll
        for (int k = 0; k < 6; ++k) { cin[k] = cnt_in[n * 6 + k]; cout[k] = cnt_out[n * 6 + k]; }
        f32x4 s0 = *(const f32x4*)&Ws_self[g * H + c0];
        f32x4 s1 = *(const f32x4*)&Ws_self[g * H + c0 + 4];
        f32x4 t0 = *(const f32x4*)&Wt_self[g * H + c0];
        f32x4 t1 = *(const f32x4*)&Wt_self[g * H + c0 + 4];
        #pragma unroll
        for (int k = 0; k < 6; ++k) {
            float ci = (float)cin[k], co = (float)cout[k];
            s0 += ci * *(const f32x4*)&Ws_nbr[k * H + c0];
            s1 += ci * *(const f32x4*)&Ws_nbr[k * H + c0 + 4];
            t0 += co * *(const f32x4*)&Wt_nbr[k * H + c0];
            t1 += co * *(const f32x4*)&Wt_nbr[k * H + c0 + 4];
        }
        bf16x8 ps, pt;
        #pragma unroll
        for (int j = 0; j < 4; ++j) {
            ps[j]     = (__bf16)fmaxf(s0[j], 0.f);
            ps[4 + j] = (__bf16)fmaxf(s1[j], 0.f);
            pt[j]     = (__bf16)fmaxf(t0[j], 0.f);
            pt[4 + j] = (__bf16)fmaxf(t1[j], 0.f);
        }
        *(bf16x8*)&st[row][c0]       = ps;
        *(bf16x8*)&st[row][128 + c0] = pt;
        if (base + row < N) {
            f32x4 z = {};
            const bool bucketed = (gate_to_gi(g) >= 0 && L >= 1 && L <= 2);
            if (bucketed) {
                // gru will write out.hf; edge atomics accumulate into agg -> zero it
                *(f32x4*)&agg[(size_t)n * H + c0]     = z;
                *(f32x4*)&agg[(size_t)n * H + c0 + 4] = z;
            } else {
                // never updated -> hf stays 0
                *(f32x4*)&out[(size_t)N * H + (size_t)n * H + c0]     = z;
                *(f32x4*)&out[(size_t)N * H + (size_t)n * H + c0 + 4] = z;
            }
        }
        __syncthreads();
        f32x4 acc[2] = {};
        #pragma unroll
        for (int kk = 0; kk < 8; ++kk) {
            bf16x8 a = *(const bf16x8*)&st[lane & 15][kk * 32 + (lane >> 4) * 8];
            #pragma unroll
            for (int j = 0; j < 2; ++j)
                acc[j] = __builtin_amdgcn_mfma_f32_16x16x32_bf16(a, bw[kk][j], acc[j], 0, 0, 0);
        }
        #pragma unroll
        for (int j = 0; j < 2; ++j) {
            int col = w * 32 + j * 16 + (lane & 15);
            #pragma unroll
            for (int r = 0; r < 4; ++r) {
                int nn = base + (lane >> 4) * 4 + r;
                if (nn < N) {
                    float v = acc[j][r] + hbc[j];
                    out[(size_t)nn * H + col] = v;
                    mir[(size_t)nn * 256 + col] = (__bf16)v;
                    mir[(size_t)nn * 256 + 128 + col] = (__bf16)0.f;  // hf = 0
                }
            }
        }
        __syncthreads();
    }
}

// ---------------- edge messages: edge-centric tiles over dst-sorted list,
//                  msg = relu(mir@W1+b1)@W2+b2, LDS segmented combine, 1 atomic/distinct-dst ----------------
template<int KHALF>
__global__ __launch_bounds__(256, 2)
void edge_msg_seg(int level, const int* __restrict__ etot,
                  const int2* __restrict__ elist, int ecap,
                  const __bf16* __restrict__ W1T, const __bf16* __restrict__ W2T,
                  const float* __restrict__ b1, const float* __restrict__ b2,
                  const __bf16* __restrict__ mir, float* __restrict__ agg) {
    const int gi = blockIdx.y;
    const int b = (level - 1) * 4 + gi;
    const int ecnt = etot[b];
    const int ntiles = (ecnt + 15) >> 4;
    if (ntiles == 0) return;

    __shared__ __bf16 st[16][264];
    __shared__ __bf16 hid[16][136];
    __shared__ float msgbuf[16][132];
    __shared__ int ssrc[16], sdst[16];
    __shared__ int leadrow[17];
    __shared__ int nlead;

    const int tid = threadIdx.x;
    const int lane = tid & 63;
    const int w = tid >> 6;
    const __bf16* w1 = W1T + (size_t)gi * 128 * 256;
    const __bf16* w2 = W2T + (size_t)gi * 128 * 128;

    bf16x8 w1f[KHALF][2], w2f[4][2];
    #pragma unroll
    for (int kk = 0; kk < KHALF; ++kk)
        #pragma unroll
        for (int j = 0; j < 2; ++j) {
            int col = w * 32 + j * 16 + (lane & 15);
            w1f[kk][j] = *(const bf16x8*)&w1[(size_t)col * 256 + kk * 32 + (lane >> 4) * 8];
        }
    #pragma unroll
    for (int kk = 0; kk < 4; ++kk)
        #pragma unroll
        for (int j = 0; j < 2; ++j) {
            int col = w * 32 + j * 16 + (lane & 15);
            w2f[kk][j] = *(const bf16x8*)&w2[(size_t)col * 128 + kk * 32 + (lane >> 4) * 8];
        }
    float b1c[2], b2c[2];
    #pragma unroll
    for (int j = 0; j < 2; ++j) {
        int col = w * 32 + j * 16 + (lane & 15);
        b1c[j] = b1[gi * H + col];
        b2c[j] = b2[gi * H + col];
    }

    for (int t = blockIdx.x; t < ntiles; t += gridDim.x) {
        const int base = t * 16;
        const int rem = min(16, ecnt - base);
        if (tid < 16) {
            int2 e = elist[b * ecap + base + min(tid, rem - 1)];
            ssrc[tid] = e.x;
            sdst[tid] = e.y;
        }
        __syncthreads();
        if (tid == 0) {
            int nl = 0;
            for (int r = 0; r < rem; ++r)
                if (r == 0 || sdst[r] != sdst[r - 1]) leadrow[nl++] = r;
            leadrow[nl] = rem;
            nlead = nl;
        }
        // gather src rows from bf16 mirror (16B chunks, no convert)
        #pragma unroll
        for (int rep = 0; rep < KHALF / 4; ++rep) {
            int idx = rep * 256 + tid;
            int r = idx / (KHALF * 4);
            int c = idx - r * (KHALF * 4);
            *(bf16x8*)&st[r][c * 8] = *(const bf16x8*)&mir[(size_t)ssrc[r] * 256 + c * 8];
        }
        __syncthreads();
        // GEMM1: hid = relu(st @ W1 + b1)
        f32x4 acc[2] = {};
        #pragma unroll
        for (int kk = 0; kk < KHALF; ++kk) {
            bf16x8 a = *(const bf16x8*)&st[lane & 15][kk * 32 + (lane >> 4) * 8];
            #pragma unroll
            for (int j = 0; j < 2; ++j)
                acc[j] = __builtin_amdgcn_mfma_f32_16x16x32_bf16(a, w1f[kk][j], acc[j], 0, 0, 0);
        }
        #pragma unroll
        for (int j = 0; j < 2; ++j) {
            int col = w * 32 + j * 16 + (lane & 15);
            #pragma unroll
            for (int r = 0; r < 4; ++r)
                hid[(lane >> 4) * 4 + r][col] = (__bf16)fmaxf(acc[j][r] + b1c[j], 0.f);
        }
        __syncthreads();
        // GEMM2: msg = hid @ W2 + b2 -> msgbuf (plain LDS stores)
        f32x4 acc2[2] = {};
        #pragma unroll
        for (int kk = 0; kk < 4; ++kk) {
            bf16x8 a = *(const bf16x8*)&hid[lane & 15][kk * 32 + (lane >> 4) * 8];
            #pragma unroll
            for (int j = 0; j < 2; ++j)
                acc2[j] = __builtin_amdgcn_mfma_f32_16x16x32_bf16(a, w2f[kk][j], acc2[j], 0, 0, 0);
        }
        #pragma unroll
        for (int j = 0; j < 2; ++j) {
            int col = w * 32 + j * 16 + (lane & 15);
            #pragma unroll
            for (int r = 0; r < 4; ++r)
                msgbuf[(lane >> 4) * 4 + r][col] = acc2[j][r] + b2c[j];
        }
        __syncthreads();
        // segmented combine: one atomic per distinct dst per column
        const int nl = nlead;
        for (int idx = tid; idx < (nl << 7); idx += 256) {
            int li = idx >> 7, c = idx & 127;
            int r0 = leadrow[li], r1 = leadrow[li + 1];
            float s = msgbuf[r0][c];
            for (int r = r0 + 1; r < r1; ++r) s += msgbuf[r][c];
            atomicAdd(&agg[(size_t)sdst[r0] * H + c], s);
        }
        __syncthreads();
    }
}

// ---------------- GRU: h = (1-z)*tanh(inn + r*bhn), x = agg; writes out(f32) + mir(bf16) ----------------
__global__ __launch_bounds__(256, 2)
void gru_mfma(const int* __restrict__ ncnt, const int* __restrict__ nbuf, int ncap,
              int level, int N,
              const __bf16* __restrict__ WihT, const float* __restrict__ bih,
              const float* __restrict__ bhh,
              const float* __restrict__ agg, float* __restrict__ out,
              __bf16* __restrict__ mir) {
    const int gi = blockIdx.y;
    const int bucket = (level - 1) * 4 + gi;
    const int cnt = min(ncnt[bucket], ncap);
    const int ntiles = (cnt + 15) >> 4;
    if (ntiles == 0) return;

    __shared__ __bf16 x[16][136];
    __shared__ int nid[16];
    const int tid = threadIdx.x;
    const int lane = tid & 63;
    const int w = tid >> 6;
    const __bf16* wih = WihT + (size_t)gi * 384 * 128;

    bf16x8 wf[4][3][2];
    #pragma unroll
    for (int kk = 0; kk < 4; ++kk)
        #pragma unroll
        for (int p = 0; p < 3; ++p)
            #pragma unroll
            for (int j = 0; j < 2; ++j) {
                int oc = p * 128 + w * 32 + j * 16 + (lane & 15);
                wf[kk][p][j] = *(const bf16x8*)&wih[(size_t)oc * 128 + kk * 32 + (lane >> 4) * 8];
            }
    float bir[2], biz[2], bin[2], bhn[2];
    #pragma unroll
    for (int j = 0; j < 2; ++j) {
        int col = w * 32 + j * 16 + (lane & 15);
        bir[j] = bih[gi * 384 + col] + bhh[gi * 384 + col];
        biz[j] = bih[gi * 384 + 128 + col] + bhh[gi * 384 + 128 + col];
        bin[j] = bih[gi * 384 + 256 + col];
        bhn[j] = bhh[gi * 384 + 256 + col];
    }

    for (int t = blockIdx.x; t < ntiles; t += gridDim.x) {
        const int base = t * 16;
        const int rem = min(16, cnt - base);
        if (tid < 16) nid[tid] = nbuf[bucket * ncap + base + min(tid, rem - 1)];
        __syncthreads();
        #pragma unroll
        for (int rep = 0; rep < 2; ++rep) {
            int idx = rep * 256 + tid;
            int row = idx >> 5, c4 = idx & 31;
            f32x4 v = *(const f32x4*)&agg[(size_t)nid[row] * H + c4 * 4];
            bf16x4 p;
            p[0] = (__bf16)v[0]; p[1] = (__bf16)v[1]; p[2] = (__bf16)v[2]; p[3] = (__bf16)v[3];
            *(bf16x4*)&x[row][c4 * 4] = p;
        }
        __syncthreads();
        f32x4 acc[3][2] = {};
        #pragma unroll
        for (int kk = 0; kk < 4; ++kk) {
            bf16x8 a = *(const bf16x8*)&x[lane & 15][kk * 32 + (lane >> 4) * 8];
            #pragma unroll
            for (int p = 0; p < 3; ++p)
                #pragma unroll
                for (int j = 0; j < 2; ++j)
                    acc[p][j] = __builtin_amdgcn_mfma_f32_16x16x32_bf16(a, wf[kk][p][j], acc[p][j], 0, 0, 0);
        }
        #pragma unroll
        for (int j = 0; j < 2; ++j) {
            int col = w * 32 + j * 16 + (lane & 15);
            #pragma unroll
            for (int r = 0; r < 4; ++r) {
                int row = (lane >> 4) * 4 + r;
                if (row >= rem) continue;
                float rr = 1.f / (1.f + expf(-(acc[0][j][r] + bir[j])));
                float zz = 1.f / (1.f + expf(-(acc[1][j][r] + biz[j])));
                float nn = tanhf(acc[2][j][r] + bin[j] + rr * bhn[j]);
                float h = (1.f - zz) * nn;
                out[(size_t)N * H + (size_t)nid[row] * H + col] = h;
                mir[(size_t)nid[row] * 256 + 128 + col] = (__bf16)h;
            }
        }
        __syncthreads();
    }
}

extern "C" void kernel_launch(void* const* d_in, const int* in_sizes, int n_in,
                              void* d_out, int out_size, void* d_ws, size_t ws_size,
                              hipStream_t stream) {
    const int*   gate    = (const int*)d_in[0];
    const int*   ei      = (const int*)d_in[1];
    const int*   lvl     = (const int*)d_in[2];
    const float* Ws_self = (const float*)d_in[4];
    const float* Ws_nbr  = (const float*)d_in[5];
    const float* Wt_self = (const float*)d_in[6];
    const float* Wt_nbr  = (const float*)d_in[7];
    const float* hs_W    = (const float*)d_in[8];
    const float* hs_b    = (const float*)d_in[9];
    const float* aW1     = (const float*)d_in[10];
    const float* ab1     = (const float*)d_in[11];
    const float* aW2     = (const float*)d_in[12];
    const float* ab2     = (const float*)d_in[13];
    const float* gWih    = (const float*)d_in[14];
    const float* gbih    = (const float*)d_in[15];
    // d_in[16] = gru_Whh unused (h == 0 at each node's single update)
    const float* gbhh    = (const float*)d_in[17];

    const int N = in_sizes[0];
    const int E = in_sizes[1] / 2;
    const int ECAP = ((E / 4) + 15) & ~15;
    const int NCAP = ((N / 4) + 15) & ~15;

    char* wsb = (char*)d_ws;
    size_t off = 0;
    float* agg = (float*)(wsb + off);         off += (size_t)N * H * sizeof(float);
    const size_t zstart = off;                // agg zeroed per-row by encoder
    int* cnt_in = (int*)(wsb + off);          off += (size_t)N * 6 * sizeof(int);
    int* cnt_out = (int*)(wsb + off);         off += (size_t)N * 6 * sizeof(int);
    int* ncnt = (int*)(wsb + off);            off += 8 * sizeof(int) + 64; off = (off + 63) & ~(size_t)63;
    const size_t zero_bytes = off - zstart;   // cnts + counters (~2.9MB), 16B-aligned region
    int* etot = (int*)(wsb + off);            off += 64;
    int* cursor = (int*)(wsb + off);          off += (size_t)N * sizeof(int); off = (off + 7) & ~(size_t)7;
    int2* elist = (int2*)(wsb + off);         off += (size_t)8 * ECAP * sizeof(int2);
    int* nbuf   = (int*)(wsb + off);          off += (size_t)8 * NCAP * sizeof(int);
    __bf16* mir = (__bf16*)(wsb + off);       off += (size_t)N * 256 * sizeof(__bf16);
    __bf16* W1T = (__bf16*)(wsb + off);       off += (size_t)4 * 128 * 256 * 2;
    __bf16* W2T = (__bf16*)(wsb + off);       off += (size_t)4 * 128 * 128 * 2;
    __bf16* WihT = (__bf16*)(wsb + off);      off += (size_t)4 * 384 * 128 * 2;
    __bf16* hsWT = (__bf16*)(wsb + off);      off += (size_t)128 * 256 * 2;

    float* out = (float*)d_out;

    // fast zero of cnt_in/cnt_out/ncnt (region is 16B-aligned and 16B-multiple)
    {
        int n16 = (int)(zero_bytes / 16);
        int blocks = min((n16 + 255) / 256, 2048);
        zero_ws<<<blocks, 256, 0, stream>>>((f32x4*)(wsb + zstart), n16);
    }
    prep_weights<<<dim3(192, 1, 13), 256, 0, stream>>>(aW1, aW2, gWih, hs_W, W1T, W2T, WihT, hsWT);
    const int nchunks = (max(E, N) + BB_CHUNK - 1) / BB_CHUNK;
    bucket_build<<<nchunks, 256, 0, stream>>>(
        gate, ei, lvl, E, N, ncnt, nbuf, NCAP, cnt_in, cnt_out);
    node_scan<<<8, 256, 0, stream>>>(ncnt, nbuf, NCAP, cnt_in, ECAP, cursor, etot);
    edge_scatter<<<(E + 255) / 256, 256, 0, stream>>>(gate, ei, lvl, E, cursor, elist);
    encoder_mfma<<<512, 256, 0, stream>>>(
        gate, lvl, cnt_in, cnt_out, Ws_self, Ws_nbr, Wt_self, Wt_nbr, hsWT, hs_b,
        out, mir, agg, N);

    // level 1: hf == 0 everywhere -> KHALF=4 (only hs K-rows of W1)
    edge_msg_seg<4><<<dim3(64, 4), 256, 0, stream>>>(
        1, etot, elist, ECAP, W1T, W2T, ab1, ab2, mir, agg);
    gru_mfma<<<dim3(64, 4), 256, 0, stream>>>(
        ncnt, nbuf, NCAP, 1, N, WihT, gbih, gbhh, agg, out, mir);
    edge_msg_seg<8><<<dim3(64, 4), 256, 0, stream>>>(
        2, etot, elist, ECAP, W1T, W2T, ab1, ab2, mir, agg);
    gru_mfma<<<dim3(64, 4), 256, 0, stream>>>(
        ncnt, nbuf, NCAP, 2, N, WihT, gbih, gbhh, agg, out, mir);
}

// Round 9
// 138.235 us; speedup vs baseline: 1.4078x; 1.4078x over previous
//
#include <hip/hip_runtime.h>

#define H 128

typedef __bf16 bf16x8 __attribute__((ext_vector_type(8)));
typedef __bf16 bf16x4 __attribute__((ext_vector_type(4)));
typedef float  f32x4  __attribute__((ext_vector_type(4)));

__device__ __forceinline__ int gate_to_gi(int g) {
    // GATE_CODES = (2, 3, 4, 1) -> gi 0..3
    switch (g) {
        case 2: return 0;
        case 3: return 1;
        case 4: return 2;
        case 1: return 3;
        default: return -1;
    }
}

// ---------------- fast zero ----------------
__global__ __launch_bounds__(256)
void zero_ws(f32x4* __restrict__ p, int n16) {
    int i = blockIdx.x * blockDim.x + threadIdx.x;
    f32x4 z = {};
    for (; i < n16; i += gridDim.x * blockDim.x) p[i] = z;
}

// ---------------- node buckets + degree histograms ----------------
#define BB_CHUNK 512
#define BB_IT (BB_CHUNK / 256)
__global__ __launch_bounds__(256)
void bucket_build(const int* __restrict__ gate, const int* __restrict__ ei,
                  const int* __restrict__ lvl, int E, int N,
                  int* __restrict__ ncnt, int* __restrict__ nbuf, int ncap,
                  int* __restrict__ cnt_in, int* __restrict__ cnt_out) {
    __shared__ int lcnt[8];
    __shared__ int lbase[8];
    const int tid = threadIdx.x;
    const int total = max(E, N);

    for (int chunk = blockIdx.x * BB_CHUNK; chunk < total; chunk += gridDim.x * BB_CHUNK) {
        if (tid < 8) lcnt[tid] = 0;
        __syncthreads();
        int nbkt[BB_IT], npos[BB_IT];
        #pragma unroll
        for (int it = 0; it < BB_IT; ++it) {
            int i = chunk + it * 256 + tid;
            nbkt[it] = -1;
            if (i < E) {
                int s = ei[i], d = ei[E + i];
                atomicAdd(&cnt_in[d * 6 + gate[s]], 1);
                atomicAdd(&cnt_out[s * 6 + gate[d]], 1);
            }
            if (i < N) {
                int gi = gate_to_gi(gate[i]);
                int L = lvl[i];
                if (gi >= 0 && L >= 1 && L <= 2) {
                    int b = (L - 1) * 4 + gi;
                    nbkt[it] = b;
                    npos[it] = atomicAdd(&lcnt[b], 1);
                }
            }
        }
        __syncthreads();
        if (tid < 8) lbase[tid] = atomicAdd(&ncnt[tid], lcnt[tid]);
        __syncthreads();
        #pragma unroll
        for (int it = 0; it < BB_IT; ++it) {
            int i = chunk + it * 256 + tid;
            if (nbkt[it] >= 0) {
                int p = lbase[nbkt[it]] + npos[it];
                if (p < ncap) nbuf[nbkt[it] * ncap + p] = i;
            }
        }
        __syncthreads();
    }
}

// ---------------- parallel per-node edge-segment allocation ----------------
// Replaces the 8-block node_scan: LDS atomicAdd gives intra-block offset,
// one global atomic per bucket per block. Segment order within bucket is
// arbitrary (only per-node contiguity matters). galloc[b] ends at bucket total.
__global__ __launch_bounds__(256)
void node_alloc(const int* __restrict__ gate, const int* __restrict__ lvl,
                const int* __restrict__ cnt_in, int N, int ecap,
                int* __restrict__ galloc, int* __restrict__ cursor) {
    __shared__ int lcnt[8];
    __shared__ int lbase[8];
    const int tid = threadIdx.x;
    for (int base = blockIdx.x * 256; base < N; base += gridDim.x * 256) {
        if (tid < 8) lcnt[tid] = 0;
        __syncthreads();
        int n = base + tid;
        int b = -1, local = 0;
        if (n < N) {
            int gi = gate_to_gi(gate[n]);
            int L = lvl[n];
            if (gi >= 0 && L >= 1 && L <= 2) {
                b = (L - 1) * 4 + gi;
                int deg = 0;
                #pragma unroll
                for (int c = 0; c < 6; ++c) deg += cnt_in[n * 6 + c];
                local = atomicAdd(&lcnt[b], deg);
            }
        }
        __syncthreads();
        if (tid < 8) lbase[tid] = atomicAdd(&galloc[tid], lcnt[tid]);
        __syncthreads();
        if (b >= 0) cursor[n] = b * ecap + lbase[b] + local;
        __syncthreads();
    }
}

// ---------------- scatter (src,dst) into per-node (dst-contiguous) edge lists ----------------
__global__ __launch_bounds__(256)
void edge_scatter(const int* __restrict__ gate, const int* __restrict__ ei,
                  const int* __restrict__ lvl, int E,
                  int* __restrict__ cursor, int2* __restrict__ elist) {
    int e = blockIdx.x * blockDim.x + threadIdx.x;
    if (e >= E) return;
    int d = ei[E + e];
    int gi = gate_to_gi(gate[d]);
    if (gi < 0) return;
    int L = lvl[d];
    if (L < 1 || L > 2) return;
    int slot = atomicAdd(&cursor[d], 1);
    elist[slot] = make_int2(ei[e], d);
}

// ---------------- weight prep: coalesced LDS 32x33 tiled transpose + bf16 ----------------
__global__ __launch_bounds__(256)
void prep_weights(const float* __restrict__ aW1, const float* __restrict__ aW2,
                  const float* __restrict__ gWih, const float* __restrict__ hsW,
                  __bf16* __restrict__ W1T, __bf16* __restrict__ W2T,
                  __bf16* __restrict__ WihT, __bf16* __restrict__ hsWT) {
    int z = blockIdx.z;
    const float* src;
    __bf16* dst;
    int K, C;
    if (z < 4)       { src = aW1 + (size_t)z * 256 * 128;       dst = W1T + (size_t)z * 128 * 256; K = 256; C = 128; }
    else if (z < 8)  { src = aW2 + (size_t)(z - 4) * 128 * 128; dst = W2T + (size_t)(z - 4) * 128 * 128; K = 128; C = 128; }
    else if (z < 12) { src = gWih + (size_t)(z - 8) * 128 * 384; dst = WihT + (size_t)(z - 8) * 384 * 128; K = 128; C = 384; }
    else             { src = hsW;                                dst = hsWT;                        K = 256; C = 128; }
    __shared__ float tile[32][33];
    const int tilesC = C >> 5;
    const int ntile = (K >> 5) * tilesC;
    const int t = blockIdx.x;
    if (t >= ntile) return;
    const int k0 = (t / tilesC) << 5;
    const int c0 = (t % tilesC) << 5;
    const int tid = threadIdx.x;
    #pragma unroll
    for (int e = 0; e < 4; ++e) {
        int pos = e * 256 + tid;
        int kk = pos >> 5, cc = pos & 31;
        tile[kk][cc] = src[(size_t)(k0 + kk) * C + c0 + cc];   // coalesced read
    }
    __syncthreads();
    #pragma unroll
    for (int e = 0; e < 4; ++e) {
        int pos = e * 256 + tid;
        int cc = pos >> 5, kk = pos & 31;
        dst[(size_t)(c0 + cc) * K + k0 + kk] = (__bf16)tile[kk][cc];   // coalesced write
    }
}

// ---------------- encoder: s,t + hs = [s,t]@hsW (MFMA); writes out(f32, incl. hf=0 for
//                  non-bucketed nodes) + mir(bf16, hf half zeroed); zeroes agg rows of bucketed nodes ----------------
__global__ __launch_bounds__(256, 2)
void encoder_mfma(const int* __restrict__ gate, const int* __restrict__ lvl,
                  const int* __restrict__ cnt_in, const int* __restrict__ cnt_out,
                  const float* __restrict__ Ws_self, const float* __restrict__ Ws_nbr,
                  const float* __restrict__ Wt_self, const float* __restrict__ Wt_nbr,
                  const __bf16* __restrict__ hsWT, const float* __restrict__ hs_b,
                  float* __restrict__ out, __bf16* __restrict__ mir,
                  float* __restrict__ agg, int N) {
    __shared__ __bf16 st[16][264];
    const int tid = threadIdx.x;
    const int lane = tid & 63;
    const int w = tid >> 6;
    const int row = tid >> 4;      // 0..15
    const int c0 = (tid & 15) * 8; // col chunk

    bf16x8 bw[8][2];
    #pragma unroll
    for (int kk = 0; kk < 8; ++kk)
        #pragma unroll
        for (int j = 0; j < 2; ++j) {
            int col = w * 32 + j * 16 + (lane & 15);
            bw[kk][j] = *(const bf16x8*)&hsWT[(size_t)col * 256 + kk * 32 + (lane >> 4) * 8];
        }
    float hbc[2];
    #pragma unroll
    for (int j = 0; j < 2; ++j) hbc[j] = hs_b[w * 32 + j * 16 + (lane & 15)];

    const int ntiles = (N + 15) >> 4;
    for (int t = blockIdx.x; t < ntiles; t += gridDim.x) {
        const int base = t * 16;
        int n = base + row;
        if (n >= N) n = N - 1;
        const int g = gate[n];
        const int L = lvl[n];
        int cin[6], cout[6];
        #pragma unroll
        for (int k = 0; k < 6; ++k) { cin[k] = cnt_in[n * 6 + k]; cout[k] = cnt_out[n * 6 + k]; }
        f32x4 s0 = *(const f32x4*)&Ws_self[g * H + c0];
        f32x4 s1 = *(const f32x4*)&Ws_self[g * H + c0 + 4];
        f32x4 t0 = *(const f32x4*)&Wt_self[g * H + c0];
        f32x4 t1 = *(const f32x4*)&Wt_self[g * H + c0 + 4];
        #pragma unroll
        for (int k = 0; k < 6; ++k) {
            float ci = (float)cin[k], co = (float)cout[k];
            s0 += ci * *(const f32x4*)&Ws_nbr[k * H + c0];
            s1 += ci * *(const f32x4*)&Ws_nbr[k * H + c0 + 4];
            t0 += co * *(const f32x4*)&Wt_nbr[k * H + c0];
            t1 += co * *(const f32x4*)&Wt_nbr[k * H + c0 + 4];
        }
        bf16x8 ps, pt;
        #pragma unroll
        for (int j = 0; j < 4; ++j) {
            ps[j]     = (__bf16)fmaxf(s0[j], 0.f);
            ps[4 + j] = (__bf16)fmaxf(s1[j], 0.f);
            pt[j]     = (__bf16)fmaxf(t0[j], 0.f);
            pt[4 + j] = (__bf16)fmaxf(t1[j], 0.f);
        }
        *(bf16x8*)&st[row][c0]       = ps;
        *(bf16x8*)&st[row][128 + c0] = pt;
        if (base + row < N) {
            f32x4 z = {};
            const bool bucketed = (gate_to_gi(g) >= 0 && L >= 1 && L <= 2);
            if (bucketed) {
                *(f32x4*)&agg[(size_t)n * H + c0]     = z;
                *(f32x4*)&agg[(size_t)n * H + c0 + 4] = z;
            } else {
                *(f32x4*)&out[(size_t)N * H + (size_t)n * H + c0]     = z;
                *(f32x4*)&out[(size_t)N * H + (size_t)n * H + c0 + 4] = z;
            }
        }
        __syncthreads();
        f32x4 acc[2] = {};
        #pragma unroll
        for (int kk = 0; kk < 8; ++kk) {
            bf16x8 a = *(const bf16x8*)&st[lane & 15][kk * 32 + (lane >> 4) * 8];
            #pragma unroll
            for (int j = 0; j < 2; ++j)
                acc[j] = __builtin_amdgcn_mfma_f32_16x16x32_bf16(a, bw[kk][j], acc[j], 0, 0, 0);
        }
        #pragma unroll
        for (int j = 0; j < 2; ++j) {
            int col = w * 32 + j * 16 + (lane & 15);
            #pragma unroll
            for (int r = 0; r < 4; ++r) {
                int nn = base + (lane >> 4) * 4 + r;
                if (nn < N) {
                    float v = acc[j][r] + hbc[j];
                    out[(size_t)nn * H + col] = v;
                    mir[(size_t)nn * 256 + col] = (__bf16)v;
                    mir[(size_t)nn * 256 + 128 + col] = (__bf16)0.f;  // hf = 0
                }
            }
        }
        __syncthreads();
    }
}

// ---------------- edge messages: edge-centric tiles over dst-contiguous list,
//                  msg = relu(mir@W1+b1)@W2+b2, LDS segmented combine, 1 atomic/distinct-dst ----------------
template<int KHALF>
__global__ __launch_bounds__(256, 2)
void edge_msg_seg(int level, const int* __restrict__ etot,
                  const int2* __restrict__ elist, int ecap,
                  const __bf16* __restrict__ W1T, const __bf16* __restrict__ W2T,
                  const float* __restrict__ b1, const float* __restrict__ b2,
                  const __bf16* __restrict__ mir, float* __restrict__ agg) {
    const int gi = blockIdx.y;
    const int b = (level - 1) * 4 + gi;
    const int ecnt = etot[b];
    const int ntiles = (ecnt + 15) >> 4;
    if (ntiles == 0) return;

    __shared__ __bf16 st[16][264];
    __shared__ __bf16 hid[16][136];
    __shared__ float msgbuf[16][132];
    __shared__ int ssrc[16], sdst[16];
    __shared__ int leadrow[17];
    __shared__ int nlead;

    const int tid = threadIdx.x;
    const int lane = tid & 63;
    const int w = tid >> 6;
    const __bf16* w1 = W1T + (size_t)gi * 128 * 256;
    const __bf16* w2 = W2T + (size_t)gi * 128 * 128;

    bf16x8 w1f[KHALF][2], w2f[4][2];
    #pragma unroll
    for (int kk = 0; kk < KHALF; ++kk)
        #pragma unroll
        for (int j = 0; j < 2; ++j) {
            int col = w * 32 + j * 16 + (lane & 15);
            w1f[kk][j] = *(const bf16x8*)&w1[(size_t)col * 256 + kk * 32 + (lane >> 4) * 8];
        }
    #pragma unroll
    for (int kk = 0; kk < 4; ++kk)
        #pragma unroll
        for (int j = 0; j < 2; ++j) {
            int col = w * 32 + j * 16 + (lane & 15);
            w2f[kk][j] = *(const bf16x8*)&w2[(size_t)col * 128 + kk * 32 + (lane >> 4) * 8];
        }
    float b1c[2], b2c[2];
    #pragma unroll
    for (int j = 0; j < 2; ++j) {
        int col = w * 32 + j * 16 + (lane & 15);
        b1c[j] = b1[gi * H + col];
        b2c[j] = b2[gi * H + col];
    }

    for (int t = blockIdx.x; t < ntiles; t += gridDim.x) {
        const int base = t * 16;
        const int rem = min(16, ecnt - base);
        if (tid < 64) {
            if (tid < 16) {
                int2 e = elist[b * ecap + base + min(tid, rem - 1)];
                ssrc[tid] = e.x;
                sdst[tid] = e.y;
            }
            // wave-0 ballot lead-row computation (replaces serial tid==0 scan)
            bool flag = (tid < rem) && (tid == 0 || sdst[tid] != sdst[tid - 1]);
            unsigned long long m = __ballot(flag);
            if (flag) {
                int rank = __popcll(m & ((1ull << tid) - 1));
                leadrow[rank] = tid;
            }
            if (tid == 0) {
                int nl = __popcll(m);
                nlead = nl;
                leadrow[nl] = rem;
            }
        }
        __syncthreads();
        // gather src rows from bf16 mirror (16B chunks)
        #pragma unroll
        for (int rep = 0; rep < KHALF / 4; ++rep) {
            int idx = rep * 256 + tid;
            int r = idx / (KHALF * 4);
            int c = idx - r * (KHALF * 4);
            *(bf16x8*)&st[r][c * 8] = *(const bf16x8*)&mir[(size_t)ssrc[r] * 256 + c * 8];
        }
        __syncthreads();
        // GEMM1: hid = relu(st @ W1 + b1)
        f32x4 acc[2] = {};
        #pragma unroll
        for (int kk = 0; kk < KHALF; ++kk) {
            bf16x8 a = *(const bf16x8*)&st[lane & 15][kk * 32 + (lane >> 4) * 8];
            #pragma unroll
            for (int j = 0; j < 2; ++j)
                acc[j] = __builtin_amdgcn_mfma_f32_16x16x32_bf16(a, w1f[kk][j], acc[j], 0, 0, 0);
        }
        #pragma unroll
        for (int j = 0; j < 2; ++j) {
            int col = w * 32 + j * 16 + (lane & 15);
            #pragma unroll
            for (int r = 0; r < 4; ++r)
                hid[(lane >> 4) * 4 + r][col] = (__bf16)fmaxf(acc[j][r] + b1c[j], 0.f);
        }
        __syncthreads();
        // GEMM2: msg = hid @ W2 + b2 -> msgbuf
        f32x4 acc2[2] = {};
        #pragma unroll
        for (int kk = 0; kk < 4; ++kk) {
            bf16x8 a = *(const bf16x8*)&hid[lane & 15][kk * 32 + (lane >> 4) * 8];
            #pragma unroll
            for (int j = 0; j < 2; ++j)
                acc2[j] = __builtin_amdgcn_mfma_f32_16x16x32_bf16(a, w2f[kk][j], acc2[j], 0, 0, 0);
        }
        #pragma unroll
        for (int j = 0; j < 2; ++j) {
            int col = w * 32 + j * 16 + (lane & 15);
            #pragma unroll
            for (int r = 0; r < 4; ++r)
                msgbuf[(lane >> 4) * 4 + r][col] = acc2[j][r] + b2c[j];
        }
        __syncthreads();
        // segmented combine: one atomic per distinct dst per column
        const int nl = nlead;
        for (int idx = tid; idx < (nl << 7); idx += 256) {
            int li = idx >> 7, c = idx & 127;
            int r0 = leadrow[li], r1 = leadrow[li + 1];
            float s = msgbuf[r0][c];
            for (int r = r0 + 1; r < r1; ++r) s += msgbuf[r][c];
            atomicAdd(&agg[(size_t)sdst[r0] * H + c], s);
        }
        __syncthreads();
    }
}

// ---------------- GRU: h = (1-z)*tanh(inn + r*bhn), x = agg; writes out(f32) + mir(bf16) ----------------
__global__ __launch_bounds__(256, 2)
void gru_mfma(const int* __restrict__ ncnt, const int* __restrict__ nbuf, int ncap,
              int level, int N,
              const __bf16* __restrict__ WihT, const float* __restrict__ bih,
              const float* __restrict__ bhh,
              const float* __restrict__ agg, float* __restrict__ out,
              __bf16* __restrict__ mir) {
    const int gi = blockIdx.y;
    const int bucket = (level - 1) * 4 + gi;
    const int cnt = min(ncnt[bucket], ncap);
    const int ntiles = (cnt + 15) >> 4;
    if (ntiles == 0) return;

    __shared__ __bf16 x[16][136];
    __shared__ int nid[16];
    const int tid = threadIdx.x;
    const int lane = tid & 63;
    const int w = tid >> 6;
    const __bf16* wih = WihT + (size_t)gi * 384 * 128;

    bf16x8 wf[4][3][2];
    #pragma unroll
    for (int kk = 0; kk < 4; ++kk)
        #pragma unroll
        for (int p = 0; p < 3; ++p)
            #pragma unroll
            for (int j = 0; j < 2; ++j) {
                int oc = p * 128 + w * 32 + j * 16 + (lane & 15);
                wf[kk][p][j] = *(const bf16x8*)&wih[(size_t)oc * 128 + kk * 32 + (lane >> 4) * 8];
            }
    float bir[2], biz[2], bin[2], bhn[2];
    #pragma unroll
    for (int j = 0; j < 2; ++j) {
        int col = w * 32 + j * 16 + (lane & 15);
        bir[j] = bih[gi * 384 + col] + bhh[gi * 384 + col];
        biz[j] = bih[gi * 384 + 128 + col] + bhh[gi * 384 + 128 + col];
        bin[j] = bih[gi * 384 + 256 + col];
        bhn[j] = bhh[gi * 384 + 256 + col];
    }

    for (int t = blockIdx.x; t < ntiles; t += gridDim.x) {
        const int base = t * 16;
        const int rem = min(16, cnt - base);
        if (tid < 16) nid[tid] = nbuf[bucket * ncap + base + min(tid, rem - 1)];
        __syncthreads();
        #pragma unroll
        for (int rep = 0; rep < 2; ++rep) {
            int idx = rep * 256 + tid;
            int row = idx >> 5, c4 = idx & 31;
            f32x4 v = *(const f32x4*)&agg[(size_t)nid[row] * H + c4 * 4];
            bf16x4 p;
            p[0] = (__bf16)v[0]; p[1] = (__bf16)v[1]; p[2] = (__bf16)v[2]; p[3] = (__bf16)v[3];
            *(bf16x4*)&x[row][c4 * 4] = p;
        }
        __syncthreads();
        f32x4 acc[3][2] = {};
        #pragma unroll
        for (int kk = 0; kk < 4; ++kk) {
            bf16x8 a = *(const bf16x8*)&x[lane & 15][kk * 32 + (lane >> 4) * 8];
            #pragma unroll
            for (int p = 0; p < 3; ++p)
                #pragma unroll
                for (int j = 0; j < 2; ++j)
                    acc[p][j] = __builtin_amdgcn_mfma_f32_16x16x32_bf16(a, wf[kk][p][j], acc[p][j], 0, 0, 0);
        }
        #pragma unroll
        for (int j = 0; j < 2; ++j) {
            int col = w * 32 + j * 16 + (lane & 15);
            #pragma unroll
            for (int r = 0; r < 4; ++r) {
                int row = (lane >> 4) * 4 + r;
                if (row >= rem) continue;
                float rr = 1.f / (1.f + expf(-(acc[0][j][r] + bir[j])));
                float zz = 1.f / (1.f + expf(-(acc[1][j][r] + biz[j])));
                float nn = tanhf(acc[2][j][r] + bin[j] + rr * bhn[j]);
                float h = (1.f - zz) * nn;
                out[(size_t)N * H + (size_t)nid[row] * H + col] = h;
                mir[(size_t)nid[row] * 256 + 128 + col] = (__bf16)h;
            }
        }
        __syncthreads();
    }
}

extern "C" void kernel_launch(void* const* d_in, const int* in_sizes, int n_in,
                              void* d_out, int out_size, void* d_ws, size_t ws_size,
                              hipStream_t stream) {
    const int*   gate    = (const int*)d_in[0];
    const int*   ei      = (const int*)d_in[1];
    const int*   lvl     = (const int*)d_in[2];
    const float* Ws_self = (const float*)d_in[4];
    const float* Ws_nbr  = (const float*)d_in[5];
    const float* Wt_self = (const float*)d_in[6];
    const float* Wt_nbr  = (const float*)d_in[7];
    const float* hs_W    = (const float*)d_in[8];
    const float* hs_b    = (const float*)d_in[9];
    const float* aW1     = (const float*)d_in[10];
    const float* ab1     = (const float*)d_in[11];
    const float* aW2     = (const float*)d_in[12];
    const float* ab2     = (const float*)d_in[13];
    const float* gWih    = (const float*)d_in[14];
    const float* gbih    = (const float*)d_in[15];
    // d_in[16] = gru_Whh unused (h == 0 at each node's single update)
    const float* gbhh    = (const float*)d_in[17];

    const int N = in_sizes[0];
    const int E = in_sizes[1] / 2;
    const int ECAP = ((E / 4) + 15) & ~15;
    const int NCAP = ((N / 4) + 15) & ~15;

    char* wsb = (char*)d_ws;
    size_t off = 0;
    float* agg = (float*)(wsb + off);         off += (size_t)N * H * sizeof(float);
    const size_t zstart = off;                // agg zeroed per-row by encoder
    int* cnt_in = (int*)(wsb + off);          off += (size_t)N * 6 * sizeof(int);
    int* cnt_out = (int*)(wsb + off);         off += (size_t)N * 6 * sizeof(int);
    int* ncnt = (int*)(wsb + off);            off += 8 * sizeof(int);
    int* galloc = (int*)(wsb + off);          off += 8 * sizeof(int); off = (off + 63) & ~(size_t)63;
    const size_t zero_bytes = off - zstart;   // cnts + ncnt + galloc (~2.9MB), 16B-multiple
    int* cursor = (int*)(wsb + off);          off += (size_t)N * sizeof(int); off = (off + 7) & ~(size_t)7;
    int2* elist = (int2*)(wsb + off);         off += (size_t)8 * ECAP * sizeof(int2);
    int* nbuf   = (int*)(wsb + off);          off += (size_t)8 * NCAP * sizeof(int);
    __bf16* mir = (__bf16*)(wsb + off);       off += (size_t)N * 256 * sizeof(__bf16);
    __bf16* W1T = (__bf16*)(wsb + off);       off += (size_t)4 * 128 * 256 * 2;
    __bf16* W2T = (__bf16*)(wsb + off);       off += (size_t)4 * 128 * 128 * 2;
    __bf16* WihT = (__bf16*)(wsb + off);      off += (size_t)4 * 384 * 128 * 2;
    __bf16* hsWT = (__bf16*)(wsb + off);      off += (size_t)128 * 256 * 2;

    float* out = (float*)d_out;

    {
        int n16 = (int)(zero_bytes / 16);
        int blocks = min((n16 + 255) / 256, 2048);
        zero_ws<<<blocks, 256, 0, stream>>>((f32x4*)(wsb + zstart), n16);
    }
    prep_weights<<<dim3(48, 1, 13), 256, 0, stream>>>(aW1, aW2, gWih, hs_W, W1T, W2T, WihT, hsWT);
    const int nchunks = (max(E, N) + BB_CHUNK - 1) / BB_CHUNK;
    bucket_build<<<nchunks, 256, 0, stream>>>(
        gate, ei, lvl, E, N, ncnt, nbuf, NCAP, cnt_in, cnt_out);
    node_alloc<<<(N + 255) / 256, 256, 0, stream>>>(gate, lvl, cnt_in, N, ECAP, galloc, cursor);
    edge_scatter<<<(E + 255) / 256, 256, 0, stream>>>(gate, ei, lvl, E, cursor, elist);
    encoder_mfma<<<512, 256, 0, stream>>>(
        gate, lvl, cnt_in, cnt_out, Ws_self, Ws_nbr, Wt_self, Wt_nbr, hsWT, hs_b,
        out, mir, agg, N);

    // level 1: hf == 0 everywhere -> KHALF=4 (only hs K-rows of W1)
    edge_msg_seg<4><<<dim3(128, 4), 256, 0, stream>>>(
        1, galloc, elist, ECAP, W1T, W2T, ab1, ab2, mir, agg);
    gru_mfma<<<dim3(64, 4), 256, 0, stream>>>(
        ncnt, nbuf, NCAP, 1, N, WihT, gbih, gbhh, agg, out, mir);
    edge_msg_seg<8><<<dim3(128, 4), 256, 0, stream>>>(
        2, galloc, elist, ECAP, W1T, W2T, ab1, ab2, mir, agg);
    gru_mfma<<<dim3(64, 4), 256, 0, stream>>>(
        ncnt, nbuf, NCAP, 2, N, WihT, gbih, gbhh, agg, out, mir);
}

// Round 10
// 131.334 us; speedup vs baseline: 1.4818x; 1.0525x over previous
//
#include <hip/hip_runtime.h>
#include <limits.h>

#define H 128

typedef __bf16 bf16x8 __attribute__((ext_vector_type(8)));
typedef __bf16 bf16x4 __attribute__((ext_vector_type(4)));
typedef float  f32x4  __attribute__((ext_vector_type(4)));

#define CUR_SENTINEL (INT_MIN / 2)

__device__ __forceinline__ int gate_to_gi(int g) {
    // GATE_CODES = (2, 3, 4, 1) -> gi 0..3
    switch (g) {
        case 2: return 0;
        case 3: return 1;
        case 4: return 2;
        case 1: return 3;
        default: return -1;
    }
}

// ---------------- weight prep (tiled transpose + bf16) fused with ws zeroing ----------------
__global__ __launch_bounds__(256)
void prep_weights(const float* __restrict__ aW1, const float* __restrict__ aW2,
                  const float* __restrict__ gWih, const float* __restrict__ hsW,
                  __bf16* __restrict__ W1T, __bf16* __restrict__ W2T,
                  __bf16* __restrict__ WihT, __bf16* __restrict__ hsWT,
                  f32x4* __restrict__ zbase, int zn16) {
    const int z = blockIdx.z;
    const int tid = threadIdx.x;
    if (z == 14) {   // zero plane: cnt_in/cnt_out/ncnt/galloc
        f32x4 zero = {};
        for (int i = blockIdx.x * 256 + tid; i < zn16; i += gridDim.x * 256) zbase[i] = zero;
        return;
    }
    const float* src;
    __bf16* dst;
    int K, C;
    if (z < 4)       { src = aW1 + (size_t)z * 256 * 128;       dst = W1T + (size_t)z * 128 * 256; K = 256; C = 128; }
    else if (z < 8)  { src = aW2 + (size_t)(z - 4) * 128 * 128; dst = W2T + (size_t)(z - 4) * 128 * 128; K = 128; C = 128; }
    else if (z < 12) { src = gWih + (size_t)(z - 8) * 128 * 384; dst = WihT + (size_t)(z - 8) * 384 * 128; K = 128; C = 384; }
    else             { src = hsW;                                dst = hsWT;                        K = 256; C = 128; }
    __shared__ float tile[32][33];
    const int tilesC = C >> 5;
    const int ntile = (K >> 5) * tilesC;
    const int t = blockIdx.x;
    if (t >= ntile) return;
    const int k0 = (t / tilesC) << 5;
    const int c0 = (t % tilesC) << 5;
    #pragma unroll
    for (int e = 0; e < 4; ++e) {
        int pos = e * 256 + tid;
        int kk = pos >> 5, cc = pos & 31;
        tile[kk][cc] = src[(size_t)(k0 + kk) * C + c0 + cc];
    }
    __syncthreads();
    #pragma unroll
    for (int e = 0; e < 4; ++e) {
        int pos = e * 256 + tid;
        int cc = pos >> 5, kk = pos & 31;
        dst[(size_t)(c0 + cc) * K + k0 + kk] = (__bf16)tile[kk][cc];
    }
}

// ---------------- degree histograms (pure edge pass, no LDS/barriers) ----------------
__global__ __launch_bounds__(256)
void hist_kernel(const int* __restrict__ gate, const int* __restrict__ ei, int E,
                 int* __restrict__ cnt_in, int* __restrict__ cnt_out) {
    int e = blockIdx.x * blockDim.x + threadIdx.x;
    if (e >= E) return;
    int s = ei[e], d = ei[E + e];
    atomicAdd(&cnt_in[d * 6 + gate[s]], 1);
    atomicAdd(&cnt_out[s * 6 + gate[d]], 1);
}

// ---------------- node pass: bucket nodes + allocate per-node edge segments + cursor ----------------
// Two-level LDS allocators: lcnt[0..7] = edge-space (degree sums), lcnt[8..15] = node slots.
// cursor[n] = segment base for bucketed nodes, CUR_SENTINEL otherwise (scatter needs no gate/lvl reads).
__global__ __launch_bounds__(256)
void node_alloc(const int* __restrict__ gate, const int* __restrict__ lvl,
                const int* __restrict__ cnt_in, int N, int ecap, int ncap,
                int* __restrict__ galloc, int* __restrict__ ncnt,
                int* __restrict__ cursor, int* __restrict__ nbuf) {
    __shared__ int lcnt[16];
    __shared__ int lbase[16];
    const int tid = threadIdx.x;
    for (int base = blockIdx.x * 256; base < N; base += gridDim.x * 256) {
        if (tid < 16) lcnt[tid] = 0;
        __syncthreads();
        int n = base + tid;
        int b = -1, local = 0, nlocal = 0;
        if (n < N) {
            int gi = gate_to_gi(gate[n]);
            int L = lvl[n];
            if (gi >= 0 && L >= 1 && L <= 2) {
                b = (L - 1) * 4 + gi;
                int deg = 0;
                #pragma unroll
                for (int c = 0; c < 6; ++c) deg += cnt_in[n * 6 + c];
                local = atomicAdd(&lcnt[b], deg);
                nlocal = atomicAdd(&lcnt[8 + b], 1);
            }
        }
        __syncthreads();
        if (tid < 8)       lbase[tid] = atomicAdd(&galloc[tid], lcnt[tid]);
        else if (tid < 16) lbase[tid] = atomicAdd(&ncnt[tid - 8], lcnt[tid]);
        __syncthreads();
        if (n < N) {
            if (b >= 0) {
                cursor[n] = b * ecap + lbase[b] + local;
                int p = lbase[8 + b] + nlocal;
                if (p < ncap) nbuf[b * ncap + p] = n;
            } else {
                cursor[n] = CUR_SENTINEL;
            }
        }
        __syncthreads();
    }
}

// ---------------- scatter (src,dst) into per-node (dst-contiguous) edge lists ----------------
__global__ __launch_bounds__(256)
void edge_scatter(const int* __restrict__ ei, int E,
                  int* __restrict__ cursor, int2* __restrict__ elist) {
    int e = blockIdx.x * blockDim.x + threadIdx.x;
    if (e >= E) return;
    int d = ei[E + e];
    int slot = atomicAdd(&cursor[d], 1);        // sentinel keeps non-bucketed negative
    if (slot >= 0) elist[slot] = make_int2(ei[e], d);
}

// ---------------- encoder: s,t + hs = [s,t]@hsW (MFMA); writes out(f32, incl. hf=0 for
//                  non-bucketed nodes) + mir(bf16, hf half zeroed); zeroes agg rows of bucketed nodes ----------------
__global__ __launch_bounds__(256, 2)
void encoder_mfma(const int* __restrict__ gate, const int* __restrict__ lvl,
                  const int* __restrict__ cnt_in, const int* __restrict__ cnt_out,
                  const float* __restrict__ Ws_self, const float* __restrict__ Ws_nbr,
                  const float* __restrict__ Wt_self, const float* __restrict__ Wt_nbr,
                  const __bf16* __restrict__ hsWT, const float* __restrict__ hs_b,
                  float* __restrict__ out, __bf16* __restrict__ mir,
                  float* __restrict__ agg, int N) {
    __shared__ __bf16 st[16][264];
    const int tid = threadIdx.x;
    const int lane = tid & 63;
    const int w = tid >> 6;
    const int row = tid >> 4;      // 0..15
    const int c0 = (tid & 15) * 8; // col chunk

    bf16x8 bw[8][2];
    #pragma unroll
    for (int kk = 0; kk < 8; ++kk)
        #pragma unroll
        for (int j = 0; j < 2; ++j) {
            int col = w * 32 + j * 16 + (lane & 15);
            bw[kk][j] = *(const bf16x8*)&hsWT[(size_t)col * 256 + kk * 32 + (lane >> 4) * 8];
        }
    float hbc[2];
    #pragma unroll
    for (int j = 0; j < 2; ++j) hbc[j] = hs_b[w * 32 + j * 16 + (lane & 15)];

    const int ntiles = (N + 15) >> 4;
    for (int t = blockIdx.x; t < ntiles; t += gridDim.x) {
        const int base = t * 16;
        int n = base + row;
        if (n >= N) n = N - 1;
        const int g = gate[n];
        const int L = lvl[n];
        int cin[6], cout[6];
        #pragma unroll
        for (int k = 0; k < 6; ++k) { cin[k] = cnt_in[n * 6 + k]; cout[k] = cnt_out[n * 6 + k]; }
        f32x4 s0 = *(const f32x4*)&Ws_self[g * H + c0];
        f32x4 s1 = *(const f32x4*)&Ws_self[g * H + c0 + 4];
        f32x4 t0 = *(const f32x4*)&Wt_self[g * H + c0];
        f32x4 t1 = *(const f32x4*)&Wt_self[g * H + c0 + 4];
        #pragma unroll
        for (int k = 0; k < 6; ++k) {
            float ci = (float)cin[k], co = (float)cout[k];
            s0 += ci * *(const f32x4*)&Ws_nbr[k * H + c0];
            s1 += ci * *(const f32x4*)&Ws_nbr[k * H + c0 + 4];
            t0 += co * *(const f32x4*)&Wt_nbr[k * H + c0];
            t1 += co * *(const f32x4*)&Wt_nbr[k * H + c0 + 4];
        }
        bf16x8 ps, pt;
        #pragma unroll
        for (int j = 0; j < 4; ++j) {
            ps[j]     = (__bf16)fmaxf(s0[j], 0.f);
            ps[4 + j] = (__bf16)fmaxf(s1[j], 0.f);
            pt[j]     = (__bf16)fmaxf(t0[j], 0.f);
            pt[4 + j] = (__bf16)fmaxf(t1[j], 0.f);
        }
        *(bf16x8*)&st[row][c0]       = ps;
        *(bf16x8*)&st[row][128 + c0] = pt;
        if (base + row < N) {
            f32x4 z = {};
            bf16x8 zb = {};
            *(bf16x8*)&mir[(size_t)n * 256 + 128 + c0] = zb;   // mir hf = 0 (vectorized)
            const bool bucketed = (gate_to_gi(g) >= 0 && L >= 1 && L <= 2);
            if (bucketed) {
                *(f32x4*)&agg[(size_t)n * H + c0]     = z;
                *(f32x4*)&agg[(size_t)n * H + c0 + 4] = z;
            } else {
                *(f32x4*)&out[(size_t)N * H + (size_t)n * H + c0]     = z;
                *(f32x4*)&out[(size_t)N * H + (size_t)n * H + c0 + 4] = z;
            }
        }
        __syncthreads();
        f32x4 acc[2] = {};
        #pragma unroll
        for (int kk = 0; kk < 8; ++kk) {
            bf16x8 a = *(const bf16x8*)&st[lane & 15][kk * 32 + (lane >> 4) * 8];
            #pragma unroll
            for (int j = 0; j < 2; ++j)
                acc[j] = __builtin_amdgcn_mfma_f32_16x16x32_bf16(a, bw[kk][j], acc[j], 0, 0, 0);
        }
        #pragma unroll
        for (int j = 0; j < 2; ++j) {
            int col = w * 32 + j * 16 + (lane & 15);
            #pragma unroll
            for (int r = 0; r < 4; ++r) {
                int nn = base + (lane >> 4) * 4 + r;
                if (nn < N) {
                    float v = acc[j][r] + hbc[j];
                    out[(size_t)nn * H + col] = v;
                    mir[(size_t)nn * 256 + col] = (__bf16)v;
                }
            }
        }
        __syncthreads();
    }
}

// ---------------- edge messages: edge-centric tiles over dst-contiguous list,
//                  msg = relu(mir@W1+b1)@W2+b2, LDS segmented combine, 1 atomic/distinct-dst ----------------
template<int KHALF>
__global__ __launch_bounds__(256, 2)
void edge_msg_seg(int level, const int* __restrict__ etot,
                  const int2* __restrict__ elist, int ecap,
                  const __bf16* __restrict__ W1T, const __bf16* __restrict__ W2T,
                  const float* __restrict__ b1, const float* __restrict__ b2,
                  const __bf16* __restrict__ mir, float* __restrict__ agg) {
    const int gi = blockIdx.y;
    const int b = (level - 1) * 4 + gi;
    const int ecnt = etot[b];
    const int ntiles = (ecnt + 15) >> 4;
    if (ntiles == 0) return;

    __shared__ __bf16 st[16][264];
    __shared__ __bf16 hid[16][136];
    __shared__ float msgbuf[16][132];
    __shared__ int ssrc[16], sdst[16];
    __shared__ int leadrow[17];
    __shared__ int nlead;

    const int tid = threadIdx.x;
    const int lane = tid & 63;
    const int w = tid >> 6;
    const __bf16* w1 = W1T + (size_t)gi * 128 * 256;
    const __bf16* w2 = W2T + (size_t)gi * 128 * 128;

    bf16x8 w1f[KHALF][2], w2f[4][2];
    #pragma unroll
    for (int kk = 0; kk < KHALF; ++kk)
        #pragma unroll
        for (int j = 0; j < 2; ++j) {
            int col = w * 32 + j * 16 + (lane & 15);
            w1f[kk][j] = *(const bf16x8*)&w1[(size_t)col * 256 + kk * 32 + (lane >> 4) * 8];
        }
    #pragma unroll
    for (int kk = 0; kk < 4; ++kk)
        #pragma unroll
        for (int j = 0; j < 2; ++j) {
            int col = w * 32 + j * 16 + (lane & 15);
            w2f[kk][j] = *(const bf16x8*)&w2[(size_t)col * 128 + kk * 32 + (lane >> 4) * 8];
        }
    float b1c[2], b2c[2];
    #pragma unroll
    for (int j = 0; j < 2; ++j) {
        int col = w * 32 + j * 16 + (lane & 15);
        b1c[j] = b1[gi * H + col];
        b2c[j] = b2[gi * H + col];
    }

    for (int t = blockIdx.x; t < ntiles; t += gridDim.x) {
        const int base = t * 16;
        const int rem = min(16, ecnt - base);
        if (tid < 64) {
            if (tid < 16) {
                int2 e = elist[b * ecap + base + min(tid, rem - 1)];
                ssrc[tid] = e.x;
                sdst[tid] = e.y;
            }
            bool flag = (tid < rem) && (tid == 0 || sdst[tid] != sdst[tid - 1]);
            unsigned long long m = __ballot(flag);
            if (flag) {
                int rank = __popcll(m & ((1ull << tid) - 1));
                leadrow[rank] = tid;
            }
            if (tid == 0) {
                int nl = __popcll(m);
                nlead = nl;
                leadrow[nl] = rem;
            }
        }
        __syncthreads();
        #pragma unroll
        for (int rep = 0; rep < KHALF / 4; ++rep) {
            int idx = rep * 256 + tid;
            int r = idx / (KHALF * 4);
            int c = idx - r * (KHALF * 4);
            *(bf16x8*)&st[r][c * 8] = *(const bf16x8*)&mir[(size_t)ssrc[r] * 256 + c * 8];
        }
        __syncthreads();
        f32x4 acc[2] = {};
        #pragma unroll
        for (int kk = 0; kk < KHALF; ++kk) {
            bf16x8 a = *(const bf16x8*)&st[lane & 15][kk * 32 + (lane >> 4) * 8];
            #pragma unroll
            for (int j = 0; j < 2; ++j)
                acc[j] = __builtin_amdgcn_mfma_f32_16x16x32_bf16(a, w1f[kk][j], acc[j], 0, 0, 0);
        }
        #pragma unroll
        for (int j = 0; j < 2; ++j) {
            int col = w * 32 + j * 16 + (lane & 15);
            #pragma unroll
            for (int r = 0; r < 4; ++r)
                hid[(lane >> 4) * 4 + r][col] = (__bf16)fmaxf(acc[j][r] + b1c[j], 0.f);
        }
        __syncthreads();
        f32x4 acc2[2] = {};
        #pragma unroll
        for (int kk = 0; kk < 4; ++kk) {
            bf16x8 a = *(const bf16x8*)&hid[lane & 15][kk * 32 + (lane >> 4) * 8];
            #pragma unroll
            for (int j = 0; j < 2; ++j)
                acc2[j] = __builtin_amdgcn_mfma_f32_16x16x32_bf16(a, w2f[kk][j], acc2[j], 0, 0, 0);
        }
        #pragma unroll
        for (int j = 0; j < 2; ++j) {
            int col = w * 32 + j * 16 + (lane & 15);
            #pragma unroll
            for (int r = 0; r < 4; ++r)
                msgbuf[(lane >> 4) * 4 + r][col] = acc2[j][r] + b2c[j];
        }
        __syncthreads();
        const int nl = nlead;
        for (int idx = tid; idx < (nl << 7); idx += 256) {
            int li = idx >> 7, c = idx & 127;
            int r0 = leadrow[li], r1 = leadrow[li + 1];
            float s = msgbuf[r0][c];
            for (int r = r0 + 1; r < r1; ++r) s += msgbuf[r][c];
            atomicAdd(&agg[(size_t)sdst[r0] * H + c], s);
        }
        __syncthreads();
    }
}

// ---------------- GRU: h = (1-z)*tanh(inn + r*bhn), x = agg; writes out(f32) + mir(bf16) ----------------
__global__ __launch_bounds__(256, 2)
void gru_mfma(const int* __restrict__ ncnt, const int* __restrict__ nbuf, int ncap,
              int level, int N,
              const __bf16* __restrict__ WihT, const float* __restrict__ bih,
              const float* __restrict__ bhh,
              const float* __restrict__ agg, float* __restrict__ out,
              __bf16* __restrict__ mir) {
    const int gi = blockIdx.y;
    const int bucket = (level - 1) * 4 + gi;
    const int cnt = min(ncnt[bucket], ncap);
    const int ntiles = (cnt + 15) >> 4;
    if (ntiles == 0) return;

    __shared__ __bf16 x[16][136];
    __shared__ int nid[16];
    const int tid = threadIdx.x;
    const int lane = tid & 63;
    const int w = tid >> 6;
    const __bf16* wih = WihT + (size_t)gi * 384 * 128;

    bf16x8 wf[4][3][2];
    #pragma unroll
    for (int kk = 0; kk < 4; ++kk)
        #pragma unroll
        for (int p = 0; p < 3; ++p)
            #pragma unroll
            for (int j = 0; j < 2; ++j) {
                int oc = p * 128 + w * 32 + j * 16 + (lane & 15);
                wf[kk][p][j] = *(const bf16x8*)&wih[(size_t)oc * 128 + kk * 32 + (lane >> 4) * 8];
            }
    float bir[2], biz[2], bin[2], bhn[2];
    #pragma unroll
    for (int j = 0; j < 2; ++j) {
        int col = w * 32 + j * 16 + (lane & 15);
        bir[j] = bih[gi * 384 + col] + bhh[gi * 384 + col];
        biz[j] = bih[gi * 384 + 128 + col] + bhh[gi * 384 + 128 + col];
        bin[j] = bih[gi * 384 + 256 + col];
        bhn[j] = bhh[gi * 384 + 256 + col];
    }

    for (int t = blockIdx.x; t < ntiles; t += gridDim.x) {
        const int base = t * 16;
        const int rem = min(16, cnt - base);
        if (tid < 16) nid[tid] = nbuf[bucket * ncap + base + min(tid, rem - 1)];
        __syncthreads();
        #pragma unroll
        for (int rep = 0; rep < 2; ++rep) {
            int idx = rep * 256 + tid;
            int row = idx >> 5, c4 = idx & 31;
            f32x4 v = *(const f32x4*)&agg[(size_t)nid[row] * H + c4 * 4];
            bf16x4 p;
            p[0] = (__bf16)v[0]; p[1] = (__bf16)v[1]; p[2] = (__bf16)v[2]; p[3] = (__bf16)v[3];
            *(bf16x4*)&x[row][c4 * 4] = p;
        }
        __syncthreads();
        f32x4 acc[3][2] = {};
        #pragma unroll
        for (int kk = 0; kk < 4; ++kk) {
            bf16x8 a = *(const bf16x8*)&x[lane & 15][kk * 32 + (lane >> 4) * 8];
            #pragma unroll
            for (int p = 0; p < 3; ++p)
                #pragma unroll
                for (int j = 0; j < 2; ++j)
                    acc[p][j] = __builtin_amdgcn_mfma_f32_16x16x32_bf16(a, wf[kk][p][j], acc[p][j], 0, 0, 0);
        }
        #pragma unroll
        for (int j = 0; j < 2; ++j) {
            int col = w * 32 + j * 16 + (lane & 15);
            #pragma unroll
            for (int r = 0; r < 4; ++r) {
                int row = (lane >> 4) * 4 + r;
                if (row >= rem) continue;
                float rr = 1.f / (1.f + expf(-(acc[0][j][r] + bir[j])));
                float zz = 1.f / (1.f + expf(-(acc[1][j][r] + biz[j])));
                float nn = tanhf(acc[2][j][r] + bin[j] + rr * bhn[j]);
                float h = (1.f - zz) * nn;
                out[(size_t)N * H + (size_t)nid[row] * H + col] = h;
                mir[(size_t)nid[row] * 256 + 128 + col] = (__bf16)h;
            }
        }
        __syncthreads();
    }
}

extern "C" void kernel_launch(void* const* d_in, const int* in_sizes, int n_in,
                              void* d_out, int out_size, void* d_ws, size_t ws_size,
                              hipStream_t stream) {
    const int*   gate    = (const int*)d_in[0];
    const int*   ei      = (const int*)d_in[1];
    const int*   lvl     = (const int*)d_in[2];
    const float* Ws_self = (const float*)d_in[4];
    const float* Ws_nbr  = (const float*)d_in[5];
    const float* Wt_self = (const float*)d_in[6];
    const float* Wt_nbr  = (const float*)d_in[7];
    const float* hs_W    = (const float*)d_in[8];
    const float* hs_b    = (const float*)d_in[9];
    const float* aW1     = (const float*)d_in[10];
    const float* ab1     = (const float*)d_in[11];
    const float* aW2     = (const float*)d_in[12];
    const float* ab2     = (const float*)d_in[13];
    const float* gWih    = (const float*)d_in[14];
    const float* gbih    = (const float*)d_in[15];
    // d_in[16] = gru_Whh unused (h == 0 at each node's single update)
    const float* gbhh    = (const float*)d_in[17];

    const int N = in_sizes[0];
    const int E = in_sizes[1] / 2;
    const int ECAP = ((E / 4) + 15) & ~15;
    const int NCAP = ((N / 4) + 15) & ~15;

    char* wsb = (char*)d_ws;
    size_t off = 0;
    float* agg = (float*)(wsb + off);         off += (size_t)N * H * sizeof(float);
    const size_t zstart = off;                // agg zeroed per-row by encoder
    int* cnt_in = (int*)(wsb + off);          off += (size_t)N * 6 * sizeof(int);
    int* cnt_out = (int*)(wsb + off);         off += (size_t)N * 6 * sizeof(int);
    int* ncnt = (int*)(wsb + off);            off += 8 * sizeof(int);
    int* galloc = (int*)(wsb + off);          off += 8 * sizeof(int); off = (off + 63) & ~(size_t)63;
    const size_t zero_bytes = off - zstart;   // cnts + ncnt + galloc (~2.9MB), 16B-multiple
    int* cursor = (int*)(wsb + off);          off += (size_t)N * sizeof(int); off = (off + 7) & ~(size_t)7;
    int2* elist = (int2*)(wsb + off);         off += (size_t)8 * ECAP * sizeof(int2);
    int* nbuf   = (int*)(wsb + off);          off += (size_t)8 * NCAP * sizeof(int);
    __bf16* mir = (__bf16*)(wsb + off);       off += (size_t)N * 256 * sizeof(__bf16);
    __bf16* W1T = (__bf16*)(wsb + off);       off += (size_t)4 * 128 * 256 * 2;
    __bf16* W2T = (__bf16*)(wsb + off);       off += (size_t)4 * 128 * 128 * 2;
    __bf16* WihT = (__bf16*)(wsb + off);      off += (size_t)4 * 384 * 128 * 2;
    __bf16* hsWT = (__bf16*)(wsb + off);      off += (size_t)128 * 256 * 2;

    float* out = (float*)d_out;

    // planes 0..13: weight transposes; plane 14: zero cnt/counter region
    prep_weights<<<dim3(48, 1, 15), 256, 0, stream>>>(
        aW1, aW2, gWih, hs_W, W1T, W2T, WihT, hsWT,
        (f32x4*)(wsb + zstart), (int)(zero_bytes / 16));
    hist_kernel<<<(E + 255) / 256, 256, 0, stream>>>(gate, ei, E, cnt_in, cnt_out);
    node_alloc<<<(N + 255) / 256, 256, 0, stream>>>(
        gate, lvl, cnt_in, N, ECAP, NCAP, galloc, ncnt, cursor, nbuf);
    edge_scatter<<<(E + 255) / 256, 256, 0, stream>>>(ei, E, cursor, elist);
    encoder_mfma<<<512, 256, 0, stream>>>(
        gate, lvl, cnt_in, cnt_out, Ws_self, Ws_nbr, Wt_self, Wt_nbr, hsWT, hs_b,
        out, mir, agg, N);

    // level 1: hf == 0 everywhere -> KHALF=4 (only hs K-rows of W1)
    edge_msg_seg<4><<<dim3(128, 4), 256, 0, stream>>>(
        1, galloc, elist, ECAP, W1T, W2T, ab1, ab2, mir, agg);
    gru_mfma<<<dim3(128, 4), 256, 0, stream>>>(
        ncnt, nbuf, NCAP, 1, N, WihT, gbih, gbhh, agg, out, mir);
    edge_msg_seg<8><<<dim3(128, 4), 256, 0, stream>>>(
        2, galloc, elist, ECAP, W1T, W2T, ab1, ab2, mir, agg);
    gru_mfma<<<dim3(128, 4), 256, 0, stream>>>(
        ncnt, nbuf, NCAP, 2, N, WihT, gbih, gbhh, agg, out, mir);
}